// Round 10
// baseline (315.748 us; speedup 1.0000x reference)
//
#include <hip/hip_runtime.h>
#include <math.h>

#define N_NODES 100000
#define N_EDGES 3200000
#define IN_DIM  128
#define OUT_DIM 64

#define BSHIFT   7
#define BNODES   128                                   // nodes per bucket
#define NBUCKETS ((N_NODES + BNODES - 1) / BNODES)     // 782
#define NBINBLK  1024
#define CHUNK    (N_EDGES / NBINBLK)                   // 3125 (exact)
#define SEGCAP   6144                                  // max edges/bucket
#define MTILES   (N_NODES / 16)                        // 6250 (exact)

typedef _Float16 half8 __attribute__((ext_vector_type(8)));
typedef float    f32x4 __attribute__((ext_vector_type(4)));

__device__ __forceinline__ float rl(float v, int l) {
    return __int_as_float(__builtin_amdgcn_readlane(__float_as_int(v), l));
}

// ---------------------------------------------------------------------------
// Kernel 1 (MFMA): base = feature @ W_lin ; u1 = tanh(base) as fp16.
// (unchanged from round 9 — verified)
// ---------------------------------------------------------------------------
__global__ __launch_bounds__(256) void gemm_base_tanh(
    const float* __restrict__ feature,
    const float* __restrict__ Wlin,     // [128][64] row-major fp32
    float* __restrict__ base,
    _Float16* __restrict__ u1h)
{
    int lane = threadIdx.x & 63;
    int wid  = (blockIdx.x * 256 + threadIdx.x) >> 6;
    if (wid >= MTILES) return;

    int mrow = lane & 15;       // A row / B col / C col
    int kb   = lane >> 4;       // k-block 0..3
    int k0   = kb * 8;

    half8 b[4][4];
#pragma unroll
    for (int s = 0; s < 4; ++s)
#pragma unroll
        for (int n = 0; n < 4; ++n)
#pragma unroll
            for (int j = 0; j < 8; ++j)
                b[s][n][j] = (_Float16)Wlin[(s * 32 + k0 + j) * OUT_DIM + n * 16 + mrow];

    int row = wid * 16 + mrow;
    const float4* fr = reinterpret_cast<const float4*>(feature + (size_t)row * IN_DIM);
    half8 a[4];
#pragma unroll
    for (int s = 0; s < 4; ++s) {
        float4 lo = fr[(s * 32 + k0) >> 2];
        float4 hi = fr[((s * 32 + k0) >> 2) + 1];
        a[s][0] = (_Float16)lo.x; a[s][1] = (_Float16)lo.y;
        a[s][2] = (_Float16)lo.z; a[s][3] = (_Float16)lo.w;
        a[s][4] = (_Float16)hi.x; a[s][5] = (_Float16)hi.y;
        a[s][6] = (_Float16)hi.z; a[s][7] = (_Float16)hi.w;
    }

    f32x4 acc[4];
#pragma unroll
    for (int n = 0; n < 4; ++n) acc[n] = (f32x4)0.f;

#pragma unroll
    for (int s = 0; s < 4; ++s)
#pragma unroll
        for (int n = 0; n < 4; ++n)
            acc[n] = __builtin_amdgcn_mfma_f32_16x16x32_f16(a[s], b[s][n], acc[n], 0, 0, 0);

#pragma unroll
    for (int n = 0; n < 4; ++n)
#pragma unroll
        for (int j = 0; j < 4; ++j) {
            int r = wid * 16 + kb * 4 + j;
            int c = n * 16 + mrow;
            float v = acc[n][j];
            base[(size_t)r * OUT_DIM + c] = v;
            u1h[(size_t)r * OUT_DIM + c] = (_Float16)tanhf(v);
        }
}

// ---------------------------------------------------------------------------
// bin_sort_local: per-block {histogram, LDS scan, LDS scatter, coalesced
// flush}.  ebuf is BLOCK-MAJOR: block b's 3125 edges, locally sorted by
// bucket, at ebuf[b*CHUNK ...] -> all global writes coalesced (no write
// amplification).  Also emits Lmat[b][k] (local exclusive offsets, row
// total == CHUNK) and accumulates global bucket totals via int atomics.
// ---------------------------------------------------------------------------
__global__ __launch_bounds__(256) void bin_sort_local(
    const int* __restrict__ src,
    const int* __restrict__ dst,
    int* __restrict__ ebuf,       // [NBINBLK][CHUNK]
    int* __restrict__ Lmat,       // [NBINBLK][NBUCKETS]
    int* __restrict__ tot)        // [NBUCKETS], pre-zeroed
{
    __shared__ int cnt[NBUCKETS];     // exclusive offsets after scan
    __shared__ int cur[NBUCKETS];     // running cursors
    __shared__ int wsum[256];
    __shared__ int seg[CHUNK];        // 12.5 KB staging

    int b = blockIdx.x;
    int t = threadIdx.x;
    int beg = b * CHUNK;

    for (int k = t; k < NBUCKETS; k += 256) cnt[k] = 0;
    __syncthreads();

    // pass 1: histogram (dst chunk -> L1/L2 warm for pass 2)
    for (int i = t; i < CHUNK; i += 256)
        atomicAdd(&cnt[dst[beg + i] >> BSHIFT], 1);
    __syncthreads();

    // scan: thread t owns slots 4t..4t+3 (1024 >= NBUCKETS)
    int b4 = t * 4;
    int s0 = (b4 + 0 < NBUCKETS) ? cnt[b4 + 0] : 0;
    int s1 = (b4 + 1 < NBUCKETS) ? cnt[b4 + 1] : 0;
    int s2 = (b4 + 2 < NBUCKETS) ? cnt[b4 + 2] : 0;
    int s3 = (b4 + 3 < NBUCKETS) ? cnt[b4 + 3] : 0;
    wsum[t] = s0 + s1 + s2 + s3;
    __syncthreads();
#pragma unroll
    for (int o = 1; o < 256; o <<= 1) {
        int v = (t >= o) ? wsum[t - o] : 0;
        __syncthreads();
        wsum[t] += v;
        __syncthreads();
    }
    int excl = (t == 0) ? 0 : wsum[t - 1];
    if (b4 + 0 < NBUCKETS) { cnt[b4 + 0] = excl; cur[b4 + 0] = excl; if (s0) atomicAdd(&tot[b4 + 0], s0); }
    excl += s0;
    if (b4 + 1 < NBUCKETS) { cnt[b4 + 1] = excl; cur[b4 + 1] = excl; if (s1) atomicAdd(&tot[b4 + 1], s1); }
    excl += s1;
    if (b4 + 2 < NBUCKETS) { cnt[b4 + 2] = excl; cur[b4 + 2] = excl; if (s2) atomicAdd(&tot[b4 + 2], s2); }
    excl += s2;
    if (b4 + 3 < NBUCKETS) { cnt[b4 + 3] = excl; cur[b4 + 3] = excl; if (s3) atomicAdd(&tot[b4 + 3], s3); }
    __syncthreads();

    // Lmat row (coalesced)
    for (int k = t; k < NBUCKETS; k += 256)
        Lmat[(size_t)b * NBUCKETS + k] = cnt[k];

    // pass 2: scatter into LDS staging (reads are L1/L2-hot)
    for (int i = t; i < CHUNK; i += 256) {
        int d = dst[beg + i];
        int k = d >> BSHIFT;
        int p = atomicAdd(&cur[k], 1);
        seg[p] = src[beg + i] | ((d & (BNODES - 1)) << 17);
    }
    __syncthreads();

    // pass 3: coalesced flush
    for (int i = t; i < CHUNK; i += 256)
        ebuf[(size_t)beg + i] = seg[i];
}

// ---------------------------------------------------------------------------
// scan_tot: exclusive scan of the 782 bucket totals -> global bucket bases.
// ---------------------------------------------------------------------------
__global__ __launch_bounds__(1024) void scan_tot(int* __restrict__ Btot)
{
    __shared__ int s[1024];
    int t = threadIdx.x;
    int v = (t < NBUCKETS) ? Btot[t] : 0;
    s[t] = v;
    __syncthreads();
#pragma unroll
    for (int off = 1; off < 1024; off <<= 1) {
        int x = (t >= off) ? s[t - off] : 0;
        __syncthreads();
        s[t] += x;
        __syncthreads();
    }
    if (t < NBUCKETS) Btot[t] = s[t] - v;       // exclusive bucket base
}

// ---------------------------------------------------------------------------
// bucket_sort: block k gathers its bucket's edges from the 1024 block-major
// mini-segments (descriptor = adjacent Lmat pair; row total == CHUNK), then
// in-LDS counting sort by node; writes csr + exact per-node offsets.
// ---------------------------------------------------------------------------
__global__ __launch_bounds__(256) void bucket_sort(
    const int* __restrict__ Lmat,
    const int* __restrict__ Bbase,    // scanned tot
    const int* __restrict__ ebuf,
    int* __restrict__ csr,
    int* __restrict__ node_off)
{
    __shared__ int seg[SEGCAP];
    __shared__ int cnt[BNODES];
    __shared__ int off[BNODES];
    __shared__ int segfill;
    int k = blockIdx.x;
    int t = threadIdx.x;

    if (t == 0) segfill = 0;
    for (int j = t; j < BNODES; j += 256) cnt[j] = 0;
    __syncthreads();

    // gather this bucket's mini-segments from all blocks
    for (int b = t; b < NBINBLK; b += 256) {
        int lo = Lmat[(size_t)b * NBUCKETS + k];
        int hi = (k + 1 < NBUCKETS) ? Lmat[(size_t)b * NBUCKETS + k + 1] : CHUNK;
        int c = hi - lo;
        if (c > 0) {
            int p = atomicAdd(&segfill, c);
            const int* e = ebuf + (size_t)b * CHUNK + lo;
            for (int j = 0; j < c; ++j) {
                int v = e[j];
                seg[p + j] = v;
                atomicAdd(&cnt[v >> 17], 1);
            }
        }
    }
    __syncthreads();

    int n = segfill;
    int beg = Bbase[k];

    if (t == 0) {
        int node0 = k * BNODES;
        int nvalid = N_NODES - node0; if (nvalid > BNODES) nvalid = BNODES;
        int excl = 0;
        for (int j = 0; j < nvalid; ++j) {
            off[j] = excl;
            node_off[node0 + j] = beg + excl;
            excl += cnt[j];
        }
        if (k == NBUCKETS - 1) node_off[N_NODES] = beg + n;
    }
    __syncthreads();

    for (int i = t; i < n; i += 256) {
        int v = seg[i];
        int p = atomicAdd(&off[v >> 17], 1);
        csr[beg + p] = v & 0x1FFFF;
    }
}

// ---------------------------------------------------------------------------
// Gather: one wave per node over fp16 u1 rows (128 B each).  (unchanged)
// ---------------------------------------------------------------------------
__global__ __launch_bounds__(256) void node_gather(
    const int* __restrict__ node_off,
    const int* __restrict__ csr,
    const half8* __restrict__ u1v,      // [N_NODES][8]
    float* __restrict__ m)
{
    int wid = (blockIdx.x * 256 + threadIdx.x) >> 6;
    if (wid >= N_NODES) return;
    int lane = threadIdx.x & 63;
    int q = lane >> 3, c = lane & 7;

    int beg = node_off[wid];
    int end = node_off[wid + 1];

    float acc[8];
#pragma unroll
    for (int i = 0; i < 8; ++i) acc[i] = 0.f;

    int e = beg + q;
    for (; e + 24 < end; e += 32) {
        int s0 = csr[e];
        int s1 = csr[e + 8];
        int s2 = csr[e + 16];
        int s3 = csr[e + 24];
        half8 a = u1v[(size_t)s0 * 8 + c];
        half8 b = u1v[(size_t)s1 * 8 + c];
        half8 g = u1v[(size_t)s2 * 8 + c];
        half8 d = u1v[(size_t)s3 * 8 + c];
#pragma unroll
        for (int i = 0; i < 8; ++i)
            acc[i] += ((float)a[i] + (float)b[i]) + ((float)g[i] + (float)d[i]);
    }
    for (; e < end; e += 8) {
        half8 a = u1v[(size_t)csr[e] * 8 + c];
#pragma unroll
        for (int i = 0; i < 8; ++i) acc[i] += (float)a[i];
    }

#pragma unroll
    for (int i = 0; i < 8; ++i) {
        acc[i] += __shfl_xor(acc[i], 8);
        acc[i] += __shfl_xor(acc[i], 16);
        acc[i] += __shfl_xor(acc[i], 32);
    }

    if (q == 0) {
        float4* mr = reinterpret_cast<float4*>(m + (size_t)wid * OUT_DIM + c * 8);
        mr[0] = make_float4(acc[0], acc[1], acc[2], acc[3]);
        mr[1] = make_float4(acc[4], acc[5], acc[6], acc[7]);
    }
}

// ---------------------------------------------------------------------------
// Kernel 3: out = tanh(base + relu(m @ W_d1) @ W_d2)  (unchanged)
// ---------------------------------------------------------------------------
__global__ __launch_bounds__(256) void dense_tanh(
    const float* __restrict__ m,
    const float* __restrict__ W1,       // [64][64]
    const float* __restrict__ W2,       // [64][64]
    const float* __restrict__ base,
    float* __restrict__ out)
{
    int lane = threadIdx.x & 63;
    int wid  = (blockIdx.x * 256 + threadIdx.x) >> 6;
    int nw   = gridDim.x * 4;

    float w1[64], w2[64];
#pragma unroll
    for (int k = 0; k < 64; ++k) w1[k] = W1[k * 64 + lane];
#pragma unroll
    for (int k = 0; k < 64; ++k) w2[k] = W2[k * 64 + lane];

    const int NPAIRS = N_NODES / 2;
    for (int p = wid; p < NPAIRS; p += nw) {
        int r0 = 2 * p, r1 = 2 * p + 1;
        float x0 = m[(size_t)r0 * 64 + lane];
        float x1 = m[(size_t)r1 * 64 + lane];

        float a0 = 0.f, a1 = 0.f;
#pragma unroll
        for (int k = 0; k < 64; ++k) {
            a0 = fmaf(rl(x0, k), w1[k], a0);
            a1 = fmaf(rl(x1, k), w1[k], a1);
        }
        float t0 = fmaxf(a0, 0.f);
        float t1 = fmaxf(a1, 0.f);

        float h0 = 0.f, h1 = 0.f;
#pragma unroll
        for (int k = 0; k < 64; ++k) {
            h0 = fmaf(rl(t0, k), w2[k], h0);
            h1 = fmaf(rl(t1, k), w2[k], h1);
        }

        float b0 = base[(size_t)r0 * 64 + lane];
        float b1 = base[(size_t)r1 * 64 + lane];
        out[(size_t)r0 * 64 + lane] = tanhf(b0 + h0);
        out[(size_t)r1 * 64 + lane] = tanhf(b1 + h1);
    }
}

// ---------------------------------------------------------------------------
extern "C" void kernel_launch(void* const* d_in, const int* in_sizes, int n_in,
                              void* d_out, int out_size, void* d_ws, size_t ws_size,
                              hipStream_t stream)
{
    const float* feature = (const float*)d_in[0];
    const int*   src     = (const int*)d_in[1];
    const int*   dst     = (const int*)d_in[2];
    const float* W_lin   = (const float*)d_in[3];
    const float* W_d1    = (const float*)d_in[4];
    const float* W_d2    = (const float*)d_in[5];
    float* out = (float*)d_out;

    const size_t NODE_F = (size_t)N_NODES * OUT_DIM;   // 6.4M elems

    float*    base     = (float*)d_ws;                          // 25.6 MB
    _Float16* u1h      = (_Float16*)(base + NODE_F);            // 12.8 MB
    float*    m        = (float*)(u1h + NODE_F);                // 25.6 MB
    int*      Lmat     = (int*)(m + NODE_F);                    // 3.2 MB
    int*      tot      = Lmat + ((size_t)NBINBLK * NBUCKETS + 4); // NBUCKETS
    int*      node_off = tot + (NBUCKETS + 4);                  // N_NODES+1
    int*      ebuf     = node_off + (N_NODES + 4);              // 12.8 MB
    int*      csr      = ebuf + N_EDGES;                        // 12.8 MB

    hipMemsetAsync(tot, 0, NBUCKETS * sizeof(int), stream);

    // iter 1 collapses: u0 == 0 -> m == 0 -> h == 0 -> u1 = tanh(feature@W_lin)
    int gemm_blocks = (MTILES + 3) / 4;                // 4 waves/block
    gemm_base_tanh<<<gemm_blocks, 256, 0, stream>>>(feature, W_lin, base, u1h);

    bin_sort_local<<<NBINBLK, 256, 0, stream>>>(src, dst, ebuf, Lmat, tot);
    scan_tot<<<1, 1024, 0, stream>>>(tot);
    bucket_sort<<<NBUCKETS, 256, 0, stream>>>(Lmat, tot, ebuf, csr, node_off);

    int gather_blocks = (int)(((size_t)N_NODES * 64 + 255) / 256);   // 25000
    node_gather<<<gather_blocks, 256, 0, stream>>>(
        node_off, csr, (const half8*)u1h, m);

    dense_tanh<<<1024, 256, 0, stream>>>(m, W_d1, W_d2, base, out);
}

// Round 11
// 207.171 us; speedup vs baseline: 1.5241x; 1.5241x over previous
//
#include <hip/hip_runtime.h>
#include <math.h>

#define N_NODES 100000
#define N_EDGES 3200000
#define IN_DIM  128
#define OUT_DIM 64

#define BSHIFT   7
#define BNODES   128                                   // nodes per bucket
#define NBUCKETS ((N_NODES + BNODES - 1) / BNODES)     // 782
#define NBINBLK  1024
#define CHUNK    (N_EDGES / NBINBLK)                   // 3125 (exact)
#define SEGCAP   6144                                  // max edges/bucket
#define MTILES   (N_NODES / 16)                        // 6250 (exact)

typedef _Float16 half8 __attribute__((ext_vector_type(8)));
typedef float    f32x4 __attribute__((ext_vector_type(4)));

__device__ __forceinline__ float rl(float v, int l) {
    return __int_as_float(__builtin_amdgcn_readlane(__float_as_int(v), l));
}

// XCD-aware swizzle: hw blocks round-robin across 8 XCDs; remap so 128
// consecutive LOGICAL blocks land on one XCD -> their adjacent bucket-major
// ebuf segments accumulate in that XCD's L2 and evict as full lines.
__device__ __forceinline__ int xcd_swz(int i) {
    return (i & 7) * (NBINBLK / 8) + (i >> 3);   // bijective: 1024 = 8*128
}

// ---------------------------------------------------------------------------
// Kernel 1 (MFMA): base = feature @ W_lin ; u1 = tanh(base) as fp16.
// (verified round 9)
// ---------------------------------------------------------------------------
__global__ __launch_bounds__(256) void gemm_base_tanh(
    const float* __restrict__ feature,
    const float* __restrict__ Wlin,     // [128][64] row-major fp32
    float* __restrict__ base,
    _Float16* __restrict__ u1h)
{
    int lane = threadIdx.x & 63;
    int wid  = (blockIdx.x * 256 + threadIdx.x) >> 6;
    if (wid >= MTILES) return;

    int mrow = lane & 15;       // A row / B col / C col
    int kb   = lane >> 4;       // k-block 0..3
    int k0   = kb * 8;

    half8 b[4][4];
#pragma unroll
    for (int s = 0; s < 4; ++s)
#pragma unroll
        for (int n = 0; n < 4; ++n)
#pragma unroll
            for (int j = 0; j < 8; ++j)
                b[s][n][j] = (_Float16)Wlin[(s * 32 + k0 + j) * OUT_DIM + n * 16 + mrow];

    int row = wid * 16 + mrow;
    const float4* fr = reinterpret_cast<const float4*>(feature + (size_t)row * IN_DIM);
    half8 a[4];
#pragma unroll
    for (int s = 0; s < 4; ++s) {
        float4 lo = fr[(s * 32 + k0) >> 2];
        float4 hi = fr[((s * 32 + k0) >> 2) + 1];
        a[s][0] = (_Float16)lo.x; a[s][1] = (_Float16)lo.y;
        a[s][2] = (_Float16)lo.z; a[s][3] = (_Float16)lo.w;
        a[s][4] = (_Float16)hi.x; a[s][5] = (_Float16)hi.y;
        a[s][6] = (_Float16)hi.z; a[s][7] = (_Float16)hi.w;
    }

    f32x4 acc[4];
#pragma unroll
    for (int n = 0; n < 4; ++n) acc[n] = (f32x4)0.f;

#pragma unroll
    for (int s = 0; s < 4; ++s)
#pragma unroll
        for (int n = 0; n < 4; ++n)
            acc[n] = __builtin_amdgcn_mfma_f32_16x16x32_f16(a[s], b[s][n], acc[n], 0, 0, 0);

#pragma unroll
    for (int n = 0; n < 4; ++n)
#pragma unroll
        for (int j = 0; j < 4; ++j) {
            int r = wid * 16 + kb * 4 + j;
            int c = n * 16 + mrow;
            float v = acc[n][j];
            base[(size_t)r * OUT_DIM + c] = v;
            u1h[(size_t)r * OUT_DIM + c] = (_Float16)tanhf(v);
        }
}

// ---------------------------------------------------------------------------
// Binning phase 1: per-block LDS histogram of dst>>7.  H bucket-major:
// H[k*NBINBLK + b].  XCD-swizzled block id.
// ---------------------------------------------------------------------------
__global__ __launch_bounds__(256) void bin_hist(
    const int* __restrict__ dst, int* __restrict__ H)
{
    __shared__ int h[NBUCKETS];
    for (int k = threadIdx.x; k < NBUCKETS; k += 256) h[k] = 0;
    __syncthreads();

    int b = xcd_swz(blockIdx.x);
    int beg = b * CHUNK, end = beg + CHUNK;
    for (int i = beg + threadIdx.x; i < end; i += 256)
        atomicAdd(&h[dst[i] >> BSHIFT], 1);
    __syncthreads();

    for (int k = threadIdx.x; k < NBUCKETS; k += 256)
        H[(size_t)k * NBINBLK + b] = h[k];
}

// ---------------------------------------------------------------------------
// Hierarchical scan of H (bucket-major), bit-exact.
// ---------------------------------------------------------------------------
__global__ __launch_bounds__(NBINBLK) void scan_local(
    int* __restrict__ H, int* __restrict__ Btot)
{
    __shared__ int s[NBINBLK];
    int k = blockIdx.x, t = threadIdx.x;
    int v = H[(size_t)k * NBINBLK + t];
    s[t] = v;
    __syncthreads();
#pragma unroll
    for (int off = 1; off < NBINBLK; off <<= 1) {
        int x = (t >= off) ? s[t - off] : 0;
        __syncthreads();
        s[t] += x;
        __syncthreads();
    }
    H[(size_t)k * NBINBLK + t] = s[t] - v;      // exclusive
    if (t == NBINBLK - 1) Btot[k] = s[t];       // inclusive total
}

__global__ __launch_bounds__(1024) void scan_tot(int* __restrict__ Btot)
{
    __shared__ int s[1024];
    int t = threadIdx.x;
    int v = (t < NBUCKETS) ? Btot[t] : 0;
    s[t] = v;
    __syncthreads();
#pragma unroll
    for (int off = 1; off < 1024; off <<= 1) {
        int x = (t >= off) ? s[t - off] : 0;
        __syncthreads();
        s[t] += x;
        __syncthreads();
    }
    if (t < NBUCKETS) Btot[t] = s[t] - v;       // exclusive bucket base
}

__global__ __launch_bounds__(NBINBLK) void add_base(
    int* __restrict__ H, const int* __restrict__ Btot)
{
    int k = blockIdx.x, t = threadIdx.x;
    H[(size_t)k * NBINBLK + t] += Btot[k];
    if (k == 0 && t == 0) H[(size_t)NBUCKETS * NBINBLK] = N_EDGES;
}

// ---------------------------------------------------------------------------
// bin_scatter: XCD-swizzled block id -> adjacent bucket-major segments are
// written from the same XCD's L2 (write-combining in L2, full-line evicts).
// ---------------------------------------------------------------------------
__global__ __launch_bounds__(256) void bin_scatter(
    const int* __restrict__ src,
    const int* __restrict__ dst,
    const int* __restrict__ H,
    int* __restrict__ ebuf)
{
    __shared__ int cur[NBUCKETS];
    int b = xcd_swz(blockIdx.x);
    for (int k = threadIdx.x; k < NBUCKETS; k += 256)
        cur[k] = H[(size_t)k * NBINBLK + b];
    __syncthreads();

    int beg = b * CHUNK, end = beg + CHUNK;
    for (int i = beg + threadIdx.x; i < end; i += 256) {
        int d = dst[i];
        int k = d >> BSHIFT;
        int p = atomicAdd(&cur[k], 1);
        // pack: src (17 bits) | dlocal (7 bits) << 17
        ebuf[p] = src[i] | ((d & (BNODES - 1)) << 17);
    }
}

// ---------------------------------------------------------------------------
// Binning phase 2: per-bucket in-LDS counting sort by node.  Rewrites ebuf
// in place (src only, node-sorted) and emits exact per-node CSR offsets.
// ---------------------------------------------------------------------------
__global__ __launch_bounds__(256) void bucket_sort(
    const int* __restrict__ H,
    int* __restrict__ ebuf,
    int* __restrict__ node_off)
{
    __shared__ int seg[SEGCAP];
    __shared__ int cnt[BNODES];
    __shared__ int off[BNODES];
    int k = blockIdx.x;
    int beg = H[(size_t)k * NBINBLK];
    int end = H[(size_t)(k + 1) * NBINBLK];
    int n = end - beg;

    for (int j = threadIdx.x; j < BNODES; j += 256) cnt[j] = 0;
    __syncthreads();

    for (int i = threadIdx.x; i < n; i += 256) {
        int v = ebuf[beg + i];
        seg[i] = v;
        atomicAdd(&cnt[v >> 17], 1);
    }
    __syncthreads();

    if (threadIdx.x == 0) {
        int node0 = k * BNODES;
        int nvalid = N_NODES - node0; if (nvalid > BNODES) nvalid = BNODES;
        int excl = 0;
        for (int j = 0; j < nvalid; ++j) {
            off[j] = excl;
            node_off[node0 + j] = beg + excl;
            excl += cnt[j];
        }
        if (k == NBUCKETS - 1) node_off[N_NODES] = end;
    }
    __syncthreads();

    for (int i = threadIdx.x; i < n; i += 256) {
        int v = seg[i];
        int p = atomicAdd(&off[v >> 17], 1);
        ebuf[beg + p] = v & 0x1FFFF;
    }
}

// ---------------------------------------------------------------------------
// Gather: one wave per node over fp16 u1 rows (128 B each).  (verified)
// ---------------------------------------------------------------------------
__global__ __launch_bounds__(256) void node_gather(
    const int* __restrict__ node_off,
    const int* __restrict__ csr,
    const half8* __restrict__ u1v,      // [N_NODES][8]
    float* __restrict__ m)
{
    int wid = (blockIdx.x * 256 + threadIdx.x) >> 6;
    if (wid >= N_NODES) return;
    int lane = threadIdx.x & 63;
    int q = lane >> 3, c = lane & 7;

    int beg = node_off[wid];
    int end = node_off[wid + 1];

    float acc[8];
#pragma unroll
    for (int i = 0; i < 8; ++i) acc[i] = 0.f;

    int e = beg + q;
    for (; e + 24 < end; e += 32) {
        int s0 = csr[e];
        int s1 = csr[e + 8];
        int s2 = csr[e + 16];
        int s3 = csr[e + 24];
        half8 a = u1v[(size_t)s0 * 8 + c];
        half8 b = u1v[(size_t)s1 * 8 + c];
        half8 g = u1v[(size_t)s2 * 8 + c];
        half8 d = u1v[(size_t)s3 * 8 + c];
#pragma unroll
        for (int i = 0; i < 8; ++i)
            acc[i] += ((float)a[i] + (float)b[i]) + ((float)g[i] + (float)d[i]);
    }
    for (; e < end; e += 8) {
        half8 a = u1v[(size_t)csr[e] * 8 + c];
#pragma unroll
        for (int i = 0; i < 8; ++i) acc[i] += (float)a[i];
    }

#pragma unroll
    for (int i = 0; i < 8; ++i) {
        acc[i] += __shfl_xor(acc[i], 8);
        acc[i] += __shfl_xor(acc[i], 16);
        acc[i] += __shfl_xor(acc[i], 32);
    }

    if (q == 0) {
        float4* mr = reinterpret_cast<float4*>(m + (size_t)wid * OUT_DIM + c * 8);
        mr[0] = make_float4(acc[0], acc[1], acc[2], acc[3]);
        mr[1] = make_float4(acc[4], acc[5], acc[6], acc[7]);
    }
}

// ---------------------------------------------------------------------------
// Kernel 3: out = tanh(base + relu(m @ W_d1) @ W_d2)  (verified)
// ---------------------------------------------------------------------------
__global__ __launch_bounds__(256) void dense_tanh(
    const float* __restrict__ m,
    const float* __restrict__ W1,       // [64][64]
    const float* __restrict__ W2,       // [64][64]
    const float* __restrict__ base,
    float* __restrict__ out)
{
    int lane = threadIdx.x & 63;
    int wid  = (blockIdx.x * 256 + threadIdx.x) >> 6;
    int nw   = gridDim.x * 4;

    float w1[64], w2[64];
#pragma unroll
    for (int k = 0; k < 64; ++k) w1[k] = W1[k * 64 + lane];
#pragma unroll
    for (int k = 0; k < 64; ++k) w2[k] = W2[k * 64 + lane];

    const int NPAIRS = N_NODES / 2;
    for (int p = wid; p < NPAIRS; p += nw) {
        int r0 = 2 * p, r1 = 2 * p + 1;
        float x0 = m[(size_t)r0 * 64 + lane];
        float x1 = m[(size_t)r1 * 64 + lane];

        float a0 = 0.f, a1 = 0.f;
#pragma unroll
        for (int k = 0; k < 64; ++k) {
            a0 = fmaf(rl(x0, k), w1[k], a0);
            a1 = fmaf(rl(x1, k), w1[k], a1);
        }
        float t0 = fmaxf(a0, 0.f);
        float t1 = fmaxf(a1, 0.f);

        float h0 = 0.f, h1 = 0.f;
#pragma unroll
        for (int k = 0; k < 64; ++k) {
            h0 = fmaf(rl(t0, k), w2[k], h0);
            h1 = fmaf(rl(t1, k), w2[k], h1);
        }

        float b0 = base[(size_t)r0 * 64 + lane];
        float b1 = base[(size_t)r1 * 64 + lane];
        out[(size_t)r0 * 64 + lane] = tanhf(b0 + h0);
        out[(size_t)r1 * 64 + lane] = tanhf(b1 + h1);
    }
}

// ---------------------------------------------------------------------------
extern "C" void kernel_launch(void* const* d_in, const int* in_sizes, int n_in,
                              void* d_out, int out_size, void* d_ws, size_t ws_size,
                              hipStream_t stream)
{
    const float* feature = (const float*)d_in[0];
    const int*   src     = (const int*)d_in[1];
    const int*   dst     = (const int*)d_in[2];
    const float* W_lin   = (const float*)d_in[3];
    const float* W_d1    = (const float*)d_in[4];
    const float* W_d2    = (const float*)d_in[5];
    float* out = (float*)d_out;

    const size_t NODE_F = (size_t)N_NODES * OUT_DIM;   // 6.4M elems

    float*    base     = (float*)d_ws;                          // 25.6 MB
    _Float16* u1h      = (_Float16*)(base + NODE_F);            // 12.8 MB
    float*    m        = (float*)(u1h + NODE_F);                // 25.6 MB
    int*      H        = (int*)(m + NODE_F);                    // 3.2 MB
    int*      Btot     = H + ((size_t)NBUCKETS * NBINBLK + 4);  // NBUCKETS
    int*      node_off = Btot + (NBUCKETS + 4);                 // N_NODES+1
    int*      ebuf     = node_off + (N_NODES + 4);              // 3.2M ints

    // iter 1 collapses: u0 == 0 -> m == 0 -> h == 0 -> u1 = tanh(feature@W_lin)
    int gemm_blocks = (MTILES + 3) / 4;                // 4 waves/block
    gemm_base_tanh<<<gemm_blocks, 256, 0, stream>>>(feature, W_lin, base, u1h);

    bin_hist  <<<NBINBLK, 256, 0, stream>>>(dst, H);
    scan_local<<<NBUCKETS, NBINBLK, 0, stream>>>(H, Btot);
    scan_tot  <<<1, 1024, 0, stream>>>(Btot);
    add_base  <<<NBUCKETS, NBINBLK, 0, stream>>>(H, Btot);
    bin_scatter<<<NBINBLK, 256, 0, stream>>>(src, dst, H, ebuf);
    bucket_sort<<<NBUCKETS, 256, 0, stream>>>(H, ebuf, node_off);

    int gather_blocks = (int)(((size_t)N_NODES * 64 + 255) / 256);   // 25000
    node_gather<<<gather_blocks, 256, 0, stream>>>(
        node_off, ebuf, (const half8*)u1h, m);

    dense_tanh<<<1024, 256, 0, stream>>>(m, W_d1, W_d2, base, out);
}

// Round 12
// 168.277 us; speedup vs baseline: 1.8764x; 1.2311x over previous
//
#include <hip/hip_runtime.h>
#include <math.h>

#define N_NODES 100000
#define N_EDGES 3200000
#define IN_DIM  128
#define OUT_DIM 64

#define BSHIFT   7
#define BNODES   128                                   // nodes per bucket
#define NBUCKETS ((N_NODES + BNODES - 1) / BNODES)     // 782
#define NBINBLK  1024
#define CHUNK    (N_EDGES / NBINBLK)                   // 3125 (exact)
#define SEGCAP   6144                                  // max edges/bucket
#define MTILES   (N_NODES / 16)                        // 6250 (exact)

typedef _Float16 half8 __attribute__((ext_vector_type(8)));
typedef float    f32x4 __attribute__((ext_vector_type(4)));

__device__ __forceinline__ float rl(float v, int l) {
    return __int_as_float(__builtin_amdgcn_readlane(__float_as_int(v), l));
}

// XCD-aware swizzle (verified round 11): 128 consecutive logical blocks per
// XCD -> bucket-major ebuf segments write-combine in one L2.
__device__ __forceinline__ int xcd_swz(int i) {
    return (i & 7) * (NBINBLK / 8) + (i >> 3);   // bijective: 1024 = 8*128
}

// ---------------------------------------------------------------------------
// Kernel 1 (MFMA): base = feature @ W_lin ; u1 = tanh(base) as fp16.
// (verified round 9)
// ---------------------------------------------------------------------------
__global__ __launch_bounds__(256) void gemm_base_tanh(
    const float* __restrict__ feature,
    const float* __restrict__ Wlin,     // [128][64] row-major fp32
    float* __restrict__ base,
    _Float16* __restrict__ u1h)
{
    int lane = threadIdx.x & 63;
    int wid  = (blockIdx.x * 256 + threadIdx.x) >> 6;
    if (wid >= MTILES) return;

    int mrow = lane & 15;       // A row / B col / C col
    int kb   = lane >> 4;       // k-block 0..3
    int k0   = kb * 8;

    half8 b[4][4];
#pragma unroll
    for (int s = 0; s < 4; ++s)
#pragma unroll
        for (int n = 0; n < 4; ++n)
#pragma unroll
            for (int j = 0; j < 8; ++j)
                b[s][n][j] = (_Float16)Wlin[(s * 32 + k0 + j) * OUT_DIM + n * 16 + mrow];

    int row = wid * 16 + mrow;
    const float4* fr = reinterpret_cast<const float4*>(feature + (size_t)row * IN_DIM);
    half8 a[4];
#pragma unroll
    for (int s = 0; s < 4; ++s) {
        float4 lo = fr[(s * 32 + k0) >> 2];
        float4 hi = fr[((s * 32 + k0) >> 2) + 1];
        a[s][0] = (_Float16)lo.x; a[s][1] = (_Float16)lo.y;
        a[s][2] = (_Float16)lo.z; a[s][3] = (_Float16)lo.w;
        a[s][4] = (_Float16)hi.x; a[s][5] = (_Float16)hi.y;
        a[s][6] = (_Float16)hi.z; a[s][7] = (_Float16)hi.w;
    }

    f32x4 acc[4];
#pragma unroll
    for (int n = 0; n < 4; ++n) acc[n] = (f32x4)0.f;

#pragma unroll
    for (int s = 0; s < 4; ++s)
#pragma unroll
        for (int n = 0; n < 4; ++n)
            acc[n] = __builtin_amdgcn_mfma_f32_16x16x32_f16(a[s], b[s][n], acc[n], 0, 0, 0);

#pragma unroll
    for (int n = 0; n < 4; ++n)
#pragma unroll
        for (int j = 0; j < 4; ++j) {
            int r = wid * 16 + kb * 4 + j;
            int c = n * 16 + mrow;
            float v = acc[n][j];
            base[(size_t)r * OUT_DIM + c] = v;
            u1h[(size_t)r * OUT_DIM + c] = (_Float16)tanhf(v);
        }
}

// ---------------------------------------------------------------------------
// Binning phase 1: per-block LDS histogram of dst>>7.  (verified)
// ---------------------------------------------------------------------------
__global__ __launch_bounds__(256) void bin_hist(
    const int* __restrict__ dst, int* __restrict__ H)
{
    __shared__ int h[NBUCKETS];
    for (int k = threadIdx.x; k < NBUCKETS; k += 256) h[k] = 0;
    __syncthreads();

    int b = xcd_swz(blockIdx.x);
    int beg = b * CHUNK, end = beg + CHUNK;
    for (int i = beg + threadIdx.x; i < end; i += 256)
        atomicAdd(&h[dst[i] >> BSHIFT], 1);
    __syncthreads();

    for (int k = threadIdx.x; k < NBUCKETS; k += 256)
        H[(size_t)k * NBINBLK + b] = h[k];
}

// ---------------------------------------------------------------------------
// Hierarchical scan of H (bucket-major), bit-exact.  (verified)
// ---------------------------------------------------------------------------
__global__ __launch_bounds__(NBINBLK) void scan_local(
    int* __restrict__ H, int* __restrict__ Btot)
{
    __shared__ int s[NBINBLK];
    int k = blockIdx.x, t = threadIdx.x;
    int v = H[(size_t)k * NBINBLK + t];
    s[t] = v;
    __syncthreads();
#pragma unroll
    for (int off = 1; off < NBINBLK; off <<= 1) {
        int x = (t >= off) ? s[t - off] : 0;
        __syncthreads();
        s[t] += x;
        __syncthreads();
    }
    H[(size_t)k * NBINBLK + t] = s[t] - v;      // exclusive
    if (t == NBINBLK - 1) Btot[k] = s[t];       // inclusive total
}

__global__ __launch_bounds__(1024) void scan_tot(int* __restrict__ Btot)
{
    __shared__ int s[1024];
    int t = threadIdx.x;
    int v = (t < NBUCKETS) ? Btot[t] : 0;
    s[t] = v;
    __syncthreads();
#pragma unroll
    for (int off = 1; off < 1024; off <<= 1) {
        int x = (t >= off) ? s[t - off] : 0;
        __syncthreads();
        s[t] += x;
        __syncthreads();
    }
    if (t < NBUCKETS) Btot[t] = s[t] - v;       // exclusive bucket base
}

__global__ __launch_bounds__(NBINBLK) void add_base(
    int* __restrict__ H, const int* __restrict__ Btot)
{
    int k = blockIdx.x, t = threadIdx.x;
    H[(size_t)k * NBINBLK + t] += Btot[k];
    if (k == 0 && t == 0) H[(size_t)NBUCKETS * NBINBLK] = N_EDGES;
}

// ---------------------------------------------------------------------------
// bin_scatter (verified with XCD swizzle)
// ---------------------------------------------------------------------------
__global__ __launch_bounds__(256) void bin_scatter(
    const int* __restrict__ src,
    const int* __restrict__ dst,
    const int* __restrict__ H,
    int* __restrict__ ebuf)
{
    __shared__ int cur[NBUCKETS];
    int b = xcd_swz(blockIdx.x);
    for (int k = threadIdx.x; k < NBUCKETS; k += 256)
        cur[k] = H[(size_t)k * NBINBLK + b];
    __syncthreads();

    int beg = b * CHUNK, end = beg + CHUNK;
    for (int i = beg + threadIdx.x; i < end; i += 256) {
        int d = dst[i];
        int k = d >> BSHIFT;
        int p = atomicAdd(&cur[k], 1);
        // pack: src (17 bits) | dlocal (7 bits) << 17
        ebuf[p] = src[i] | ((d & (BNODES - 1)) << 17);
    }
}

// ---------------------------------------------------------------------------
// bucket_sort (verified)
// ---------------------------------------------------------------------------
__global__ __launch_bounds__(256) void bucket_sort(
    const int* __restrict__ H,
    int* __restrict__ ebuf,
    int* __restrict__ node_off)
{
    __shared__ int seg[SEGCAP];
    __shared__ int cnt[BNODES];
    __shared__ int off[BNODES];
    int k = blockIdx.x;
    int beg = H[(size_t)k * NBINBLK];
    int end = H[(size_t)(k + 1) * NBINBLK];
    int n = end - beg;

    for (int j = threadIdx.x; j < BNODES; j += 256) cnt[j] = 0;
    __syncthreads();

    for (int i = threadIdx.x; i < n; i += 256) {
        int v = ebuf[beg + i];
        seg[i] = v;
        atomicAdd(&cnt[v >> 17], 1);
    }
    __syncthreads();

    if (threadIdx.x == 0) {
        int node0 = k * BNODES;
        int nvalid = N_NODES - node0; if (nvalid > BNODES) nvalid = BNODES;
        int excl = 0;
        for (int j = 0; j < nvalid; ++j) {
            off[j] = excl;
            node_off[node0 + j] = beg + excl;
            excl += cnt[j];
        }
        if (k == NBUCKETS - 1) node_off[N_NODES] = end;
    }
    __syncthreads();

    for (int i = threadIdx.x; i < n; i += 256) {
        int v = seg[i];
        int p = atomicAdd(&off[v >> 17], 1);
        ebuf[beg + p] = v & 0x1FFFF;
    }
}

// ---------------------------------------------------------------------------
// Gather: one wave per node over fp16 u1 rows (128 B each).  (verified)
// ---------------------------------------------------------------------------
__global__ __launch_bounds__(256) void node_gather(
    const int* __restrict__ node_off,
    const int* __restrict__ csr,
    const half8* __restrict__ u1v,      // [N_NODES][8]
    float* __restrict__ m)
{
    int wid = (blockIdx.x * 256 + threadIdx.x) >> 6;
    if (wid >= N_NODES) return;
    int lane = threadIdx.x & 63;
    int q = lane >> 3, c = lane & 7;

    int beg = node_off[wid];
    int end = node_off[wid + 1];

    float acc[8];
#pragma unroll
    for (int i = 0; i < 8; ++i) acc[i] = 0.f;

    int e = beg + q;
    for (; e + 24 < end; e += 32) {
        int s0 = csr[e];
        int s1 = csr[e + 8];
        int s2 = csr[e + 16];
        int s3 = csr[e + 24];
        half8 a = u1v[(size_t)s0 * 8 + c];
        half8 b = u1v[(size_t)s1 * 8 + c];
        half8 g = u1v[(size_t)s2 * 8 + c];
        half8 d = u1v[(size_t)s3 * 8 + c];
#pragma unroll
        for (int i = 0; i < 8; ++i)
            acc[i] += ((float)a[i] + (float)b[i]) + ((float)g[i] + (float)d[i]);
    }
    for (; e < end; e += 8) {
        half8 a = u1v[(size_t)csr[e] * 8 + c];
#pragma unroll
        for (int i = 0; i < 8; ++i) acc[i] += (float)a[i];
    }

#pragma unroll
    for (int i = 0; i < 8; ++i) {
        acc[i] += __shfl_xor(acc[i], 8);
        acc[i] += __shfl_xor(acc[i], 16);
        acc[i] += __shfl_xor(acc[i], 32);
    }

    if (q == 0) {
        float4* mr = reinterpret_cast<float4*>(m + (size_t)wid * OUT_DIM + c * 8);
        mr[0] = make_float4(acc[0], acc[1], acc[2], acc[3]);
        mr[1] = make_float4(acc[4], acc[5], acc[6], acc[7]);
    }
}

// ---------------------------------------------------------------------------
// Kernel 3 (MFMA): out = tanh(base + relu(m @ W_d1) @ W_d2)
// One wave per 16-row tile; both 64x64 layers as 16x16x32 MFMA chains
// (fp16 in / fp32 accum).  Inter-layer relayout (C/D frag -> A frag) via a
// per-wave 16x72 fp16 LDS tile (pad breaks power-of-2 bank stride); intra-
// wave ds_write->ds_read ordering is compiler-enforced (lgkmcnt), no barrier.
// ---------------------------------------------------------------------------
__global__ __launch_bounds__(256) void dense_tanh(
    const float* __restrict__ m,
    const float* __restrict__ W1,       // [64][64]
    const float* __restrict__ W2,       // [64][64]
    const float* __restrict__ base,
    float* __restrict__ out)
{
    __shared__ _Float16 tl[4][16][72];  // 9 KB: per-wave transpose tile
    int lane = threadIdx.x & 63;
    int w    = threadIdx.x >> 6;        // wave in block
    int wid  = (blockIdx.x * 256 + threadIdx.x) >> 6;
    if (wid >= MTILES) return;

    int mrow = lane & 15;
    int kb   = lane >> 4;
    int k0   = kb * 8;

    // B-frags for both layers (fp16): bX[s][n][j] = WX[s*32+k0+j][n*16+mrow]
    half8 b1[2][4], b2[2][4];
#pragma unroll
    for (int s = 0; s < 2; ++s)
#pragma unroll
        for (int n = 0; n < 4; ++n)
#pragma unroll
            for (int j = 0; j < 8; ++j) {
                b1[s][n][j] = (_Float16)W1[(s * 32 + k0 + j) * 64 + n * 16 + mrow];
                b2[s][n][j] = (_Float16)W2[(s * 32 + k0 + j) * 64 + n * 16 + mrow];
            }

    // A-frags from m (fp32 -> fp16)
    int row = wid * 16 + mrow;
    const float4* mr = reinterpret_cast<const float4*>(m + (size_t)row * 64);
    half8 a[2];
#pragma unroll
    for (int s = 0; s < 2; ++s) {
        float4 lo = mr[(s * 32 + k0) >> 2];
        float4 hi = mr[((s * 32 + k0) >> 2) + 1];
        a[s][0] = (_Float16)lo.x; a[s][1] = (_Float16)lo.y;
        a[s][2] = (_Float16)lo.z; a[s][3] = (_Float16)lo.w;
        a[s][4] = (_Float16)hi.x; a[s][5] = (_Float16)hi.y;
        a[s][6] = (_Float16)hi.z; a[s][7] = (_Float16)hi.w;
    }

    // layer 1: t = relu(m @ W1)
    f32x4 acc1[4];
#pragma unroll
    for (int n = 0; n < 4; ++n) acc1[n] = (f32x4)0.f;
#pragma unroll
    for (int s = 0; s < 2; ++s)
#pragma unroll
        for (int n = 0; n < 4; ++n)
            acc1[n] = __builtin_amdgcn_mfma_f32_16x16x32_f16(a[s], b1[s][n], acc1[n], 0, 0, 0);

    // C/D frag -> LDS (row = kb*4+j, col = n*16+mrow), relu applied
#pragma unroll
    for (int n = 0; n < 4; ++n)
#pragma unroll
        for (int j = 0; j < 4; ++j)
            tl[w][kb * 4 + j][n * 16 + mrow] = (_Float16)fmaxf(acc1[n][j], 0.f);

    // LDS -> A-frags for layer 2: lane reads t[mrow][s*32+k0 .. +7] (16 B)
    half8 a2[2];
#pragma unroll
    for (int s = 0; s < 2; ++s)
        a2[s] = *reinterpret_cast<const half8*>(&tl[w][mrow][s * 32 + k0]);

    // layer 2: h = t @ W2
    f32x4 acc2[4];
#pragma unroll
    for (int n = 0; n < 4; ++n) acc2[n] = (f32x4)0.f;
#pragma unroll
    for (int s = 0; s < 2; ++s)
#pragma unroll
        for (int n = 0; n < 4; ++n)
            acc2[n] = __builtin_amdgcn_mfma_f32_16x16x32_f16(a2[s], b2[s][n], acc2[n], 0, 0, 0);

    // epilogue: out = tanh(base + h)
#pragma unroll
    for (int n = 0; n < 4; ++n)
#pragma unroll
        for (int j = 0; j < 4; ++j) {
            int r = wid * 16 + kb * 4 + j;
            int c = n * 16 + mrow;
            out[(size_t)r * 64 + c] = tanhf(base[(size_t)r * 64 + c] + acc2[n][j]);
        }
}

// ---------------------------------------------------------------------------
extern "C" void kernel_launch(void* const* d_in, const int* in_sizes, int n_in,
                              void* d_out, int out_size, void* d_ws, size_t ws_size,
                              hipStream_t stream)
{
    const float* feature = (const float*)d_in[0];
    const int*   src     = (const int*)d_in[1];
    const int*   dst     = (const int*)d_in[2];
    const float* W_lin   = (const float*)d_in[3];
    const float* W_d1    = (const float*)d_in[4];
    const float* W_d2    = (const float*)d_in[5];
    float* out = (float*)d_out;

    const size_t NODE_F = (size_t)N_NODES * OUT_DIM;   // 6.4M elems

    float*    base     = (float*)d_ws;                          // 25.6 MB
    _Float16* u1h      = (_Float16*)(base + NODE_F);            // 12.8 MB
    float*    m        = (float*)(u1h + NODE_F);                // 25.6 MB
    int*      H        = (int*)(m + NODE_F);                    // 3.2 MB
    int*      Btot     = H + ((size_t)NBUCKETS * NBINBLK + 4);  // NBUCKETS
    int*      node_off = Btot + (NBUCKETS + 4);                 // N_NODES+1
    int*      ebuf     = node_off + (N_NODES + 4);              // 3.2M ints

    // iter 1 collapses: u0 == 0 -> m == 0 -> h == 0 -> u1 = tanh(feature@W_lin)
    int gemm_blocks = (MTILES + 3) / 4;                // 4 waves/block
    gemm_base_tanh<<<gemm_blocks, 256, 0, stream>>>(feature, W_lin, base, u1h);

    bin_hist  <<<NBINBLK, 256, 0, stream>>>(dst, H);
    scan_local<<<NBUCKETS, NBINBLK, 0, stream>>>(H, Btot);
    scan_tot  <<<1, 1024, 0, stream>>>(Btot);
    add_base  <<<NBUCKETS, NBINBLK, 0, stream>>>(H, Btot);
    bin_scatter<<<NBINBLK, 256, 0, stream>>>(src, dst, H, ebuf);
    bucket_sort<<<NBUCKETS, 256, 0, stream>>>(H, ebuf, node_off);

    int gather_blocks = (int)(((size_t)N_NODES * 64 + 255) / 256);   // 25000
    node_gather<<<gather_blocks, 256, 0, stream>>>(
        node_off, ebuf, (const half8*)u1h, m);

    dense_tanh<<<gemm_blocks, 256, 0, stream>>>(m, W_d1, W_d2, base, out);
}